// Round 17
// baseline (67.610 us; speedup 1.0000x reference)
//
#include <hip/hip_runtime.h>
#include <hip/hip_bf16.h>

#define NN 4096
#define KD 256
#define NH 8
#define DD 64
#define HD 512   // NH*DD
#define SLOPE 0.2f
#define NB 2048  // rank buckets

// monotone bijection float -> sortable u32 (exact)
__device__ __forceinline__ unsigned sortkey(float f) {
    unsigned b = __float_as_uint(f);
    return b ^ ((unsigned)(((int)b) >> 31) | 0x80000000u);
}
// monotone (non-decreasing) float -> bucket
__device__ __forceinline__ int bucketOf(float t) {
    int b = (int)((t + 8.0f) * 128.0f);
    return b < 0 ? 0 : (b > NB - 1 ? NB - 1 : b);
}

// ---- GEMM (64x64 tiles, BK=64: 8 barriers total) + fused s,t epilogue. ----
__global__ __launch_bounds__(256) void gemm_st(const float* __restrict__ x,
                                               const float* __restrict__ W,
                                               const float* __restrict__ attn,
                                               float* __restrict__ Wx,
                                               float* __restrict__ sH,
                                               float* __restrict__ tH) {
    const int b = blockIdx.x;                 // 0..511
    const int bmTile = (b & 7) * 8 + ((b >> 3) & 7);   // 0..63
    const int h = b >> 6;                     // 0..7
    const int bn = h * 64;
    const int bm = bmTile * 64;
    __shared__ float As[64][68];
    __shared__ float Bs[64][68];
    const int tid = threadIdx.x;
    const int tx = tid & 15, ty = tid >> 4;
    const int srow = tid >> 2;                // 0..63
    const int skq  = (tid & 3) * 16;          // 0,16,32,48
    float acc[4][4] = {};
    for (int k0 = 0; k0 < KD; k0 += 64) {
        float4 av[4], bv[4];
#pragma unroll
        for (int q = 0; q < 4; ++q) {
            av[q] = *(const float4*)&x[(bm + srow) * KD + k0 + skq + q * 4];
            bv[q] = *(const float4*)&W[(bn + srow) * KD + k0 + skq + q * 4];
        }
        __syncthreads();
#pragma unroll
        for (int q = 0; q < 4; ++q) {
            As[skq + q * 4 + 0][srow] = av[q].x;
            As[skq + q * 4 + 1][srow] = av[q].y;
            As[skq + q * 4 + 2][srow] = av[q].z;
            As[skq + q * 4 + 3][srow] = av[q].w;
            Bs[skq + q * 4 + 0][srow] = bv[q].x;
            Bs[skq + q * 4 + 1][srow] = bv[q].y;
            Bs[skq + q * 4 + 2][srow] = bv[q].z;
            Bs[skq + q * 4 + 3][srow] = bv[q].w;
        }
        __syncthreads();
#pragma unroll
        for (int kk = 0; kk < 64; ++kk) {
            float4 a = *(const float4*)&As[kk][ty * 4];
            float4 bb = *(const float4*)&Bs[kk][tx * 4];
            acc[0][0] += a.x * bb.x; acc[0][1] += a.x * bb.y; acc[0][2] += a.x * bb.z; acc[0][3] += a.x * bb.w;
            acc[1][0] += a.y * bb.x; acc[1][1] += a.y * bb.y; acc[1][2] += a.y * bb.z; acc[1][3] += a.y * bb.w;
            acc[2][0] += a.z * bb.x; acc[2][1] += a.z * bb.y; acc[2][2] += a.z * bb.z; acc[2][3] += a.z * bb.w;
            acc[3][0] += a.w * bb.x; acc[3][1] += a.w * bb.y; acc[3][2] += a.w * bb.z; acc[3][3] += a.w * bb.w;
        }
    }
#pragma unroll
    for (int m = 0; m < 4; ++m)
        *(float4*)&Wx[(bm + ty * 4 + m) * HD + bn + tx * 4] = *(const float4*)&acc[m][0];
    float4 as4 = *(const float4*)&attn[h * 128 + tx * 4];
    float4 at4 = *(const float4*)&attn[h * 128 + 64 + tx * 4];
#pragma unroll
    for (int m = 0; m < 4; ++m) {
        float s = acc[m][0] * as4.x + acc[m][1] * as4.y + acc[m][2] * as4.z + acc[m][3] * as4.w;
        float t = acc[m][0] * at4.x + acc[m][1] * at4.y + acc[m][2] * at4.z + acc[m][3] * at4.w;
#pragma unroll
        for (int off = 1; off < 16; off <<= 1) {
            s += __shfl_xor(s, off, 16);
            t += __shfl_xor(t, off, 16);
        }
        if (tx == 0) {
            sH[h * NN + bm + ty * 4 + m] = s;
            tH[h * NN + bm + ty * 4 + m] = t;
        }
    }
}

// ---- bucketed counting-sort rank + scatter + cs ---------------------------
__global__ __launch_bounds__(1024) void rank_scatter(const float* __restrict__ tH,
                                                     const float* __restrict__ sH,
                                                     int* __restrict__ sortedIdx,
                                                     float* __restrict__ expT,
                                                     float* __restrict__ expT2,
                                                     int* __restrict__ cIdx) {
    const int h = blockIdx.x;
    const int tid = threadIdx.x;
    const int lane = tid & 63, wv = tid >> 6;
    __shared__ int hist[NB];
    __shared__ int wsum[16], woff[16];
    __shared__ unsigned bkey[NN];
    __shared__ unsigned short bidx[NN];
    for (int p = tid; p < NB; p += 1024) hist[p] = 0;
    float tv[4]; unsigned kv[4]; int bv[4];
    __syncthreads();
#pragma unroll
    for (int e = 0; e < 4; ++e) {
        int p = e * 1024 + tid;
        float t = tH[h * NN + p];
        tv[e] = t;
        kv[e] = sortkey(t);
        bv[e] = bucketOf(t);
        atomicAdd(&hist[bv[e]], 1);
    }
    __syncthreads();
    int a0 = hist[2 * tid], a1 = hist[2 * tid + 1];
    int ts = a0 + a1;
    int sc = ts;
#pragma unroll
    for (int o = 1; o < 64; o <<= 1) { int n = __shfl_up(sc, o, 64); if (lane >= o) sc += n; }
    if (lane == 63) wsum[wv] = sc;
    __syncthreads();
    if (tid == 0) { int acc = 0; for (int w = 0; w < 16; ++w) { woff[w] = acc; acc += wsum[w]; } }
    __syncthreads();
    int excl = sc - ts + woff[wv];
    hist[2 * tid]     = excl;
    hist[2 * tid + 1] = excl + a0;
    __syncthreads();
#pragma unroll
    for (int e = 0; e < 4; ++e) {
        int slot = atomicAdd(&hist[bv[e]], 1);
        bkey[slot] = kv[e];
        bidx[slot] = (unsigned short)(e * 1024 + tid);
    }
    __syncthreads();
#pragma unroll
    for (int e = 0; e < 4; ++e) {
        const int p = e * 1024 + tid;
        const int b = bv[e];
        const unsigned k = kv[e];
        const int start = b ? hist[b - 1] : 0;
        const int end = hist[b];
        int r = start;
        for (int s = start; s < end; ++s) {
            unsigned ks = bkey[s];
            r += (ks < k) | ((ks == k) & (bidx[s] < p));
        }
        sortedIdx[h * NN + r] = p;
        expT [h * NN + r] = expf(tv[e]);
        expT2[h * NN + r] = expf(SLOPE * tv[e]);
    }
#pragma unroll
    for (int e = 0; e < 4; ++e) {
        const int i = e * 1024 + tid;
        const float negS = -sH[h * NN + i];
        const unsigned kt = sortkey(negS);
        const int b = bucketOf(negS);
        const int start = b ? hist[b - 1] : 0;
        const int end = hist[b];
        int cs = start;
        for (int s = start; s < end; ++s) cs += (bkey[s] <= kt);
        cIdx[h * NN + i] = cs;
    }
}

// ---- gather Wx in sorted order; chunk-local exclusive prefixes in regs ---
__global__ __launch_bounds__(256) void local_prefix(const float* __restrict__ Wx,
                                                    const int* __restrict__ sortedIdx,
                                                    const float* __restrict__ expT,
                                                    const float* __restrict__ expT2,
                                                    float* __restrict__ localW,
                                                    float* __restrict__ localW2,
                                                    float* __restrict__ chunkTotW,
                                                    float* __restrict__ chunkTotW2,
                                                    float* __restrict__ localZ,
                                                    float* __restrict__ localZ2,
                                                    float* __restrict__ chunkZtot,
                                                    float* __restrict__ chunkZtot2) {
    const int c = blockIdx.x, h = blockIdx.y;
    const int tid = threadIdx.x;
    const int wid = tid >> 6, d = tid & 63;
    const int base = h * NN + c * 64;
    __shared__ float sums[4][64], sums2[4][64];
    float run = 0.f, run2 = 0.f;
    float ex[16], ex2[16];
#pragma unroll
    for (int kk = 0; kk < 16; ++kk) {
        int k = wid * 16 + kk;
        int j = sortedIdx[base + k];
        float w  = expT[base + k];
        float w2 = expT2[base + k];
        float v = Wx[j * HD + h * DD + d];
        ex[kk]  = run;  run  += w  * v;
        ex2[kk] = run2; run2 += w2 * v;
    }
    sums[wid][d] = run; sums2[wid][d] = run2;
    __syncthreads();
    float off = 0.f, off2 = 0.f;
    for (int w = 0; w < 4; ++w)
        if (w < wid) { off += sums[w][d]; off2 += sums2[w][d]; }
#pragma unroll
    for (int kk = 0; kk < 16; ++kk) {
        int k = wid * 16 + kk;
        localW [(h * NN + c * 64 + k) * 64 + d] = ex[kk]  + off;
        localW2[(h * NN + c * 64 + k) * 64 + d] = ex2[kk] + off2;
    }
    if (wid == 3) {
        chunkTotW [(h * 64 + c) * 64 + d] = off  + run;
        chunkTotW2[(h * 64 + c) * 64 + d] = off2 + run2;
    }
    if (wid == 0) {
        float z0 = expT[base + d];
        float z = z0;
#pragma unroll
        for (int o = 1; o < 64; o <<= 1) { float n = __shfl_up(z, o, 64); if (d >= o) z += n; }
        localZ[h * NN + c * 64 + d] = z - z0;
        if (d == 63) chunkZtot[h * 64 + c] = z;
    } else if (wid == 1) {
        float z0 = expT2[base + d];
        float z = z0;
#pragma unroll
        for (int o = 1; o < 64; o <<= 1) { float n = __shfl_up(z, o, 64); if (d >= o) z += n; }
        localZ2[h * NN + c * 64 + d] = z - z0;
        if (d == 63) chunkZtot2[h * 64 + c] = z;
    }
}

// ---- output: in-block chunk scan (segmented) + streaming lookups ---------
// grid (64, NH), 256 threads; block handles 64 i's. Stages RAW chunk totals
// (32 KB, L2-hot) and scans them in LDS: 4 waves x 16-chunk serial segments
// + cross-wave offsets; Z-scans via shfl. No fences, no atomics.
__global__ __launch_bounds__(256) void out_kernel(const float* __restrict__ sH,
                                                  const int* __restrict__ cIdx,
                                                  const float* __restrict__ localW,
                                                  const float* __restrict__ localW2,
                                                  const float* __restrict__ localZ,
                                                  const float* __restrict__ localZ2,
                                                  const float* __restrict__ chunkTotW,
                                                  const float* __restrict__ chunkTotW2,
                                                  const float* __restrict__ chunkZtot,
                                                  const float* __restrict__ chunkZtot2,
                                                  float* __restrict__ out) {
    const int h  = blockIdx.y;
    const int ig = blockIdx.x;            // 0..63 (i-group of 64)
    const int tid = threadIdx.x;
    const int d = tid & 63, wv = tid >> 6;
    __shared__ __align__(16) float scW[65][64];
    __shared__ __align__(16) float scW2[65][64];
    __shared__ float psum[2][4][64];
    __shared__ float scZ[65], scZ2[65];
    // stage raw chunk totals (rows 0..63 are the first 4096 floats of scW)
    {
        const float4* cw  = (const float4*)&chunkTotW [h * 4096];
        const float4* cw2 = (const float4*)&chunkTotW2[h * 4096];
        float4* dw  = (float4*)&scW [0][0];
        float4* dw2 = (float4*)&scW2[0][0];
        for (int p = tid; p < 1024; p += 256) { dw[p] = cw[p]; dw2[p] = cw2[p]; }
        if (tid < 64)       scZ [tid]      = chunkZtot [h * 64 + tid];
        else if (tid < 128) scZ2[tid - 64] = chunkZtot2[h * 64 + tid - 64];
    }
    __syncthreads();
    // segmented exclusive scan over 64 chunks (wave wv owns chunks wv*16..+15)
    float segTot, segTot2;
    {
        const int c0 = wv * 16;
        float acc = 0.f, acc2 = 0.f;
#pragma unroll
        for (int q = 0; q < 16; ++q) {
            float t  = scW [c0 + q][d]; scW [c0 + q][d] = acc;  acc  += t;
            float t2 = scW2[c0 + q][d]; scW2[c0 + q][d] = acc2; acc2 += t2;
        }
        segTot = acc; segTot2 = acc2;
        psum[0][wv][d] = acc; psum[1][wv][d] = acc2;
    }
    __syncthreads();
    {
        float off = 0.f, off2 = 0.f;
        for (int w = 0; w < wv; ++w) { off += psum[0][w][d]; off2 += psum[1][w][d]; }
        const int c0 = wv * 16;
#pragma unroll
        for (int q = 0; q < 16; ++q) { scW[c0 + q][d] += off; scW2[c0 + q][d] += off2; }
        if (wv == 3) { scW[64][d] = off + segTot; scW2[64][d] = off2 + segTot2; }
    }
    // Z scans (shfl, waves 0 and 1)
    if (tid < 64) {
        float z0 = scZ[tid]; float z = z0;
#pragma unroll
        for (int o = 1; o < 64; o <<= 1) { float n = __shfl_up(z, o, 64); if (tid >= o) z += n; }
        scZ[tid] = z - z0;
        if (tid == 63) scZ[64] = z;
    } else if (tid < 128) {
        int l = tid - 64;
        float z0 = scZ2[l]; float z = z0;
#pragma unroll
        for (int o = 1; o < 64; o <<= 1) { float n = __shfl_up(z, o, 64); if (l >= o) z += n; }
        scZ2[l] = z - z0;
        if (l == 63) scZ2[64] = z;
    }
    __syncthreads();
    // streaming lookups: 16 iterations x 4 i's (one per wave)
#pragma unroll 4
    for (int p = 0; p < 16; ++p) {
        const int i = ig * 64 + p * 4 + wv;
        const float sv = sH[h * NN + i];
        const int c = cIdx[h * NN + i];
        const float es  = expf(sv);
        const float es2 = expf(SLOPE * sv);
        float wpos, wneg, zp, zn;
        if (c == NN) {
            wpos = 0.f; zp = 0.f;
            wneg = scW2[64][d];
            zn   = scZ2[64];
        } else {
            float pw  = localW [(h * NN + c) * 64 + d] + scW [c >> 6][d];
            float pw2 = localW2[(h * NN + c) * 64 + d] + scW2[c >> 6][d];
            wpos = scW[64][d] - pw;
            wneg = pw2;
            float pz  = localZ [h * NN + c] + scZ [c >> 6];
            float pz2 = localZ2[h * NN + c] + scZ2[c >> 6];
            zp = scZ[64] - pz;
            zn = pz2;
        }
        out[i * HD + h * DD + d] = (es * wpos + es2 * wneg) / (es * zp + es2 * zn);
    }
}

extern "C" void kernel_launch(void* const* d_in, const int* in_sizes, int n_in,
                              void* d_out, int out_size, void* d_ws, size_t ws_size,
                              hipStream_t stream) {
    const float* x    = (const float*)d_in[0];
    const float* W    = (const float*)d_in[1];
    const float* attn = (const float*)d_in[2];
    float* out = (float*)d_out;

    float* ws = (float*)d_ws;
    size_t o = 0;
    float* Wx        = ws + o; o += (size_t)NN * HD;
    float* sH        = ws + o; o += (size_t)NH * NN;
    float* tH        = ws + o; o += (size_t)NH * NN;
    float* expT      = ws + o; o += (size_t)NH * NN;
    float* expT2     = ws + o; o += (size_t)NH * NN;
    int*   sortedIdx = (int*)(ws + o); o += (size_t)NH * NN;
    int*   cIdx      = (int*)(ws + o); o += (size_t)NH * NN;
    float* localZ    = ws + o; o += (size_t)NH * NN;
    float* localZ2   = ws + o; o += (size_t)NH * NN;
    float* chunkTotW  = ws + o; o += (size_t)NH * 64 * 64;
    float* chunkTotW2 = ws + o; o += (size_t)NH * 64 * 64;
    float* chunkZtot  = ws + o; o += (size_t)NH * 64;
    float* chunkZtot2 = ws + o; o += (size_t)NH * 64;
    float* localW  = ws + o; o += (size_t)NH * NN * 64;
    float* localW2 = ws + o; o += (size_t)NH * NN * 64;

    gemm_st<<<dim3(512), dim3(256), 0, stream>>>(x, W, attn, Wx, sH, tH);
    rank_scatter<<<dim3(NH), dim3(1024), 0, stream>>>(tH, sH, sortedIdx, expT, expT2, cIdx);
    local_prefix<<<dim3(64, NH), dim3(256), 0, stream>>>(Wx, sortedIdx, expT, expT2, localW, localW2,
                                                         chunkTotW, chunkTotW2, localZ, localZ2, chunkZtot, chunkZtot2);
    out_kernel<<<dim3(64, NH), dim3(256), 0, stream>>>(sH, cIdx, localW, localW2, localZ, localZ2,
                                                       chunkTotW, chunkTotW2, chunkZtot, chunkZtot2, out);
}

// Round 18
// 63.419 us; speedup vs baseline: 1.0661x; 1.0661x over previous
//
#include <hip/hip_runtime.h>
#include <hip/hip_bf16.h>

#define NN 4096
#define KD 256
#define NH 8
#define DD 64
#define HD 512   // NH*DD
#define SLOPE 0.2f
#define NB 2048  // rank buckets

// monotone bijection float -> sortable u32 (exact)
__device__ __forceinline__ unsigned sortkey(float f) {
    unsigned b = __float_as_uint(f);
    return b ^ ((unsigned)(((int)b) >> 31) | 0x80000000u);
}
// monotone (non-decreasing) float -> bucket
__device__ __forceinline__ int bucketOf(float t) {
    int b = (int)((t + 8.0f) * 128.0f);
    return b < 0 ? 0 : (b > NB - 1 ? NB - 1 : b);
}

// ---- GEMM (64x64 tiles, BK=64: 8 barriers total) + fused s,t epilogue. ----
__global__ __launch_bounds__(256) void gemm_st(const float* __restrict__ x,
                                               const float* __restrict__ W,
                                               const float* __restrict__ attn,
                                               float* __restrict__ Wx,
                                               float* __restrict__ sH,
                                               float* __restrict__ tH) {
    const int b = blockIdx.x;                 // 0..511
    const int bmTile = (b & 7) * 8 + ((b >> 3) & 7);   // 0..63
    const int h = b >> 6;                     // 0..7
    const int bn = h * 64;
    const int bm = bmTile * 64;
    __shared__ float As[64][68];
    __shared__ float Bs[64][68];
    const int tid = threadIdx.x;
    const int tx = tid & 15, ty = tid >> 4;
    const int srow = tid >> 2;                // 0..63
    const int skq  = (tid & 3) * 16;          // 0,16,32,48
    float acc[4][4] = {};
    for (int k0 = 0; k0 < KD; k0 += 64) {
        float4 av[4], bv[4];
#pragma unroll
        for (int q = 0; q < 4; ++q) {
            av[q] = *(const float4*)&x[(bm + srow) * KD + k0 + skq + q * 4];
            bv[q] = *(const float4*)&W[(bn + srow) * KD + k0 + skq + q * 4];
        }
        __syncthreads();
#pragma unroll
        for (int q = 0; q < 4; ++q) {
            As[skq + q * 4 + 0][srow] = av[q].x;
            As[skq + q * 4 + 1][srow] = av[q].y;
            As[skq + q * 4 + 2][srow] = av[q].z;
            As[skq + q * 4 + 3][srow] = av[q].w;
            Bs[skq + q * 4 + 0][srow] = bv[q].x;
            Bs[skq + q * 4 + 1][srow] = bv[q].y;
            Bs[skq + q * 4 + 2][srow] = bv[q].z;
            Bs[skq + q * 4 + 3][srow] = bv[q].w;
        }
        __syncthreads();
#pragma unroll
        for (int kk = 0; kk < 64; ++kk) {
            float4 a = *(const float4*)&As[kk][ty * 4];
            float4 bb = *(const float4*)&Bs[kk][tx * 4];
            acc[0][0] += a.x * bb.x; acc[0][1] += a.x * bb.y; acc[0][2] += a.x * bb.z; acc[0][3] += a.x * bb.w;
            acc[1][0] += a.y * bb.x; acc[1][1] += a.y * bb.y; acc[1][2] += a.y * bb.z; acc[1][3] += a.y * bb.w;
            acc[2][0] += a.z * bb.x; acc[2][1] += a.z * bb.y; acc[2][2] += a.z * bb.z; acc[2][3] += a.z * bb.w;
            acc[3][0] += a.w * bb.x; acc[3][1] += a.w * bb.y; acc[3][2] += a.w * bb.z; acc[3][3] += a.w * bb.w;
        }
    }
#pragma unroll
    for (int m = 0; m < 4; ++m)
        *(float4*)&Wx[(bm + ty * 4 + m) * HD + bn + tx * 4] = *(const float4*)&acc[m][0];
    float4 as4 = *(const float4*)&attn[h * 128 + tx * 4];
    float4 at4 = *(const float4*)&attn[h * 128 + 64 + tx * 4];
#pragma unroll
    for (int m = 0; m < 4; ++m) {
        float s = acc[m][0] * as4.x + acc[m][1] * as4.y + acc[m][2] * as4.z + acc[m][3] * as4.w;
        float t = acc[m][0] * at4.x + acc[m][1] * at4.y + acc[m][2] * at4.z + acc[m][3] * at4.w;
#pragma unroll
        for (int off = 1; off < 16; off <<= 1) {
            s += __shfl_xor(s, off, 16);
            t += __shfl_xor(t, off, 16);
        }
        if (tx == 0) {
            sH[h * NN + bm + ty * 4 + m] = s;
            tH[h * NN + bm + ty * 4 + m] = t;
        }
    }
}

// ---- bucketed counting-sort rank + scatter + cs ---------------------------
__global__ __launch_bounds__(1024) void rank_scatter(const float* __restrict__ tH,
                                                     const float* __restrict__ sH,
                                                     int* __restrict__ sortedIdx,
                                                     float* __restrict__ expT,
                                                     float* __restrict__ expT2,
                                                     int* __restrict__ cIdx) {
    const int h = blockIdx.x;
    const int tid = threadIdx.x;
    const int lane = tid & 63, wv = tid >> 6;
    __shared__ int hist[NB];
    __shared__ int wsum[16], woff[16];
    __shared__ unsigned bkey[NN];
    __shared__ unsigned short bidx[NN];
    for (int p = tid; p < NB; p += 1024) hist[p] = 0;
    float tv[4]; unsigned kv[4]; int bv[4];
    __syncthreads();
#pragma unroll
    for (int e = 0; e < 4; ++e) {
        int p = e * 1024 + tid;
        float t = tH[h * NN + p];
        tv[e] = t;
        kv[e] = sortkey(t);
        bv[e] = bucketOf(t);
        atomicAdd(&hist[bv[e]], 1);
    }
    __syncthreads();
    int a0 = hist[2 * tid], a1 = hist[2 * tid + 1];
    int ts = a0 + a1;
    int sc = ts;
#pragma unroll
    for (int o = 1; o < 64; o <<= 1) { int n = __shfl_up(sc, o, 64); if (lane >= o) sc += n; }
    if (lane == 63) wsum[wv] = sc;
    __syncthreads();
    if (tid == 0) { int acc = 0; for (int w = 0; w < 16; ++w) { woff[w] = acc; acc += wsum[w]; } }
    __syncthreads();
    int excl = sc - ts + woff[wv];
    hist[2 * tid]     = excl;
    hist[2 * tid + 1] = excl + a0;
    __syncthreads();
#pragma unroll
    for (int e = 0; e < 4; ++e) {
        int slot = atomicAdd(&hist[bv[e]], 1);
        bkey[slot] = kv[e];
        bidx[slot] = (unsigned short)(e * 1024 + tid);
    }
    __syncthreads();
#pragma unroll
    for (int e = 0; e < 4; ++e) {
        const int p = e * 1024 + tid;
        const int b = bv[e];
        const unsigned k = kv[e];
        const int start = b ? hist[b - 1] : 0;
        const int end = hist[b];
        int r = start;
        for (int s = start; s < end; ++s) {
            unsigned ks = bkey[s];
            r += (ks < k) | ((ks == k) & (bidx[s] < p));
        }
        sortedIdx[h * NN + r] = p;
        expT [h * NN + r] = expf(tv[e]);
        expT2[h * NN + r] = expf(SLOPE * tv[e]);
    }
#pragma unroll
    for (int e = 0; e < 4; ++e) {
        const int i = e * 1024 + tid;
        const float negS = -sH[h * NN + i];
        const unsigned kt = sortkey(negS);
        const int b = bucketOf(negS);
        const int start = b ? hist[b - 1] : 0;
        const int end = hist[b];
        int cs = start;
        for (int s = start; s < end; ++s) cs += (bkey[s] <= kt);
        cIdx[h * NN + i] = cs;
    }
}

// ---- gather Wx in sorted order; chunk-local exclusive prefixes in regs ---
__global__ __launch_bounds__(256) void local_prefix(const float* __restrict__ Wx,
                                                    const int* __restrict__ sortedIdx,
                                                    const float* __restrict__ expT,
                                                    const float* __restrict__ expT2,
                                                    float* __restrict__ localW,
                                                    float* __restrict__ localW2,
                                                    float* __restrict__ chunkTotW,
                                                    float* __restrict__ chunkTotW2,
                                                    float* __restrict__ localZ,
                                                    float* __restrict__ localZ2,
                                                    float* __restrict__ chunkZtot,
                                                    float* __restrict__ chunkZtot2) {
    const int c = blockIdx.x, h = blockIdx.y;
    const int tid = threadIdx.x;
    const int wid = tid >> 6, d = tid & 63;
    const int base = h * NN + c * 64;
    __shared__ float sums[4][64], sums2[4][64];
    float run = 0.f, run2 = 0.f;
    float ex[16], ex2[16];
#pragma unroll
    for (int kk = 0; kk < 16; ++kk) {
        int k = wid * 16 + kk;
        int j = sortedIdx[base + k];
        float w  = expT[base + k];
        float w2 = expT2[base + k];
        float v = Wx[j * HD + h * DD + d];
        ex[kk]  = run;  run  += w  * v;
        ex2[kk] = run2; run2 += w2 * v;
    }
    sums[wid][d] = run; sums2[wid][d] = run2;
    __syncthreads();
    float off = 0.f, off2 = 0.f;
    for (int w = 0; w < 4; ++w)
        if (w < wid) { off += sums[w][d]; off2 += sums2[w][d]; }
#pragma unroll
    for (int kk = 0; kk < 16; ++kk) {
        int k = wid * 16 + kk;
        localW [(h * NN + c * 64 + k) * 64 + d] = ex[kk]  + off;
        localW2[(h * NN + c * 64 + k) * 64 + d] = ex2[kk] + off2;
    }
    if (wid == 3) {
        chunkTotW [(h * 64 + c) * 64 + d] = off  + run;
        chunkTotW2[(h * 64 + c) * 64 + d] = off2 + run2;
    }
    if (wid == 0) {
        float z0 = expT[base + d];
        float z = z0;
#pragma unroll
        for (int o = 1; o < 64; o <<= 1) { float n = __shfl_up(z, o, 64); if (d >= o) z += n; }
        localZ[h * NN + c * 64 + d] = z - z0;
        if (d == 63) chunkZtot[h * 64 + c] = z;
    } else if (wid == 1) {
        float z0 = expT2[base + d];
        float z = z0;
#pragma unroll
        for (int o = 1; o < 64; o <<= 1) { float n = __shfl_up(z, o, 64); if (d >= o) z += n; }
        localZ2[h * NN + c * 64 + d] = z - z0;
        if (d == 63) chunkZtot2[h * 64 + c] = z;
    }
}

// ---- per-head scan of chunk totals (in place) + grand totals -------------
__global__ __launch_bounds__(256) void chunk_scan(float* __restrict__ chunkTotW,
                                                  float* __restrict__ chunkTotW2,
                                                  float* __restrict__ chunkZtot,
                                                  float* __restrict__ chunkZtot2,
                                                  float* __restrict__ totW,
                                                  float* __restrict__ totW2,
                                                  float* __restrict__ Ztot,
                                                  float* __restrict__ Ztot2) {
    const int h = blockIdx.x;
    const int tid = threadIdx.x;
    const int lane = tid & 63;
    __shared__ float cw[64 * 64];
    __shared__ float cw2[64 * 64];
    __shared__ float zb[64], zb2[64];
#pragma unroll
    for (int it = 0; it < 16; ++it) {
        int lin = it * 256 + tid;
        cw[lin]  = chunkTotW [h * 4096 + lin];
        cw2[lin] = chunkTotW2[h * 4096 + lin];
    }
    if (tid >= 128 && tid < 192) zb[lane]  = chunkZtot [h * 64 + lane];
    if (tid >= 192)              zb2[lane] = chunkZtot2[h * 64 + lane];
    __syncthreads();
    if (tid < 64) {
        float acc = 0.f;
        for (int c = 0; c < 64; ++c) { int idx = c * 64 + tid; float t = cw[idx]; cw[idx] = acc; acc += t; }
        totW[h * 64 + tid] = acc;
    } else if (tid < 128) {
        int d = tid - 64;
        float acc = 0.f;
        for (int c = 0; c < 64; ++c) { int idx = c * 64 + d; float t = cw2[idx]; cw2[idx] = acc; acc += t; }
        totW2[h * 64 + d] = acc;
    } else if (tid < 192) {
        float z0 = zb[lane];
        float z = z0;
#pragma unroll
        for (int o = 1; o < 64; o <<= 1) { float n = __shfl_up(z, o, 64); if (lane >= o) z += n; }
        chunkZtot[h * 64 + lane] = z - z0;
        if (lane == 63) Ztot[h] = z;
    } else {
        float z0 = zb2[lane];
        float z = z0;
#pragma unroll
        for (int o = 1; o < 64; o <<= 1) { float n = __shfl_up(z, o, 64); if (lane >= o) z += n; }
        chunkZtot2[h * 64 + lane] = z - z0;
        if (lane == 63) Ztot2[h] = z;
    }
    __syncthreads();
#pragma unroll
    for (int it = 0; it < 16; ++it) {
        int lin = it * 256 + tid;
        chunkTotW [h * 4096 + lin] = cw[lin];
        chunkTotW2[h * 4096 + lin] = cw2[lin];
    }
}

// ---- output: pure streaming lookups --------------------------------------
__global__ __launch_bounds__(256) void out_kernel(const float* __restrict__ sH,
                                                  const int* __restrict__ cIdx,
                                                  const float* __restrict__ localW,
                                                  const float* __restrict__ localW2,
                                                  const float* __restrict__ chunkTotW,
                                                  const float* __restrict__ chunkTotW2,
                                                  const float* __restrict__ localZ,
                                                  const float* __restrict__ localZ2,
                                                  const float* __restrict__ chunkZtot,
                                                  const float* __restrict__ chunkZtot2,
                                                  const float* __restrict__ totW,
                                                  const float* __restrict__ totW2,
                                                  const float* __restrict__ Ztot,
                                                  const float* __restrict__ Ztot2,
                                                  float* __restrict__ out) {
    const int h = blockIdx.y;
    const int i = blockIdx.x * 4 + (threadIdx.x >> 6);
    const int d = threadIdx.x & 63;
    const float sv = sH[h * NN + i];
    const int c = cIdx[h * NN + i];
    const float es  = expf(sv);
    const float es2 = expf(SLOPE * sv);
    float wpos, wneg, zp, zn;
    if (c == NN) {
        wpos = 0.f; zp = 0.f;
        wneg = totW2[h * 64 + d];
        zn   = Ztot2[h];
    } else {
        float pw  = localW [(h * NN + c) * 64 + d] + chunkTotW [(h * 64 + (c >> 6)) * 64 + d];
        float pw2 = localW2[(h * NN + c) * 64 + d] + chunkTotW2[(h * 64 + (c >> 6)) * 64 + d];
        wpos = totW[h * 64 + d] - pw;
        wneg = pw2;
        float pz  = localZ [h * NN + c] + chunkZtot [h * 64 + (c >> 6)];
        float pz2 = localZ2[h * NN + c] + chunkZtot2[h * 64 + (c >> 6)];
        zp = Ztot[h] - pz;
        zn = pz2;
    }
    out[i * HD + h * DD + d] = (es * wpos + es2 * wneg) / (es * zp + es2 * zn);
}

extern "C" void kernel_launch(void* const* d_in, const int* in_sizes, int n_in,
                              void* d_out, int out_size, void* d_ws, size_t ws_size,
                              hipStream_t stream) {
    const float* x    = (const float*)d_in[0];
    const float* W    = (const float*)d_in[1];
    const float* attn = (const float*)d_in[2];
    float* out = (float*)d_out;

    float* ws = (float*)d_ws;
    size_t o = 0;
    float* Wx        = ws + o; o += (size_t)NN * HD;
    float* sH        = ws + o; o += (size_t)NH * NN;
    float* tH        = ws + o; o += (size_t)NH * NN;
    float* expT      = ws + o; o += (size_t)NH * NN;
    float* expT2     = ws + o; o += (size_t)NH * NN;
    int*   sortedIdx = (int*)(ws + o); o += (size_t)NH * NN;
    int*   cIdx      = (int*)(ws + o); o += (size_t)NH * NN;
    float* localZ    = ws + o; o += (size_t)NH * NN;
    float* localZ2   = ws + o; o += (size_t)NH * NN;
    float* chunkTotW  = ws + o; o += (size_t)NH * 64 * 64;
    float* chunkTotW2 = ws + o; o += (size_t)NH * 64 * 64;
    float* chunkZtot  = ws + o; o += (size_t)NH * 64;
    float* chunkZtot2 = ws + o; o += (size_t)NH * 64;
    float* totW   = ws + o; o += (size_t)NH * 64;
    float* totW2  = ws + o; o += (size_t)NH * 64;
    float* Ztot   = ws + o; o += 64;
    float* Ztot2  = ws + o; o += 64;
    float* localW  = ws + o; o += (size_t)NH * NN * 64;
    float* localW2 = ws + o; o += (size_t)NH * NN * 64;

    gemm_st<<<dim3(512), dim3(256), 0, stream>>>(x, W, attn, Wx, sH, tH);
    rank_scatter<<<dim3(NH), dim3(1024), 0, stream>>>(tH, sH, sortedIdx, expT, expT2, cIdx);
    local_prefix<<<dim3(64, NH), dim3(256), 0, stream>>>(Wx, sortedIdx, expT, expT2, localW, localW2,
                                                         chunkTotW, chunkTotW2, localZ, localZ2, chunkZtot, chunkZtot2);
    chunk_scan<<<dim3(NH), dim3(256), 0, stream>>>(chunkTotW, chunkTotW2, chunkZtot, chunkZtot2,
                                                   totW, totW2, Ztot, Ztot2);
    out_kernel<<<dim3(NN / 4, NH), dim3(256), 0, stream>>>(sH, cIdx, localW, localW2, chunkTotW, chunkTotW2,
                                                           localZ, localZ2, chunkZtot, chunkZtot2,
                                                           totW, totW2, Ztot, Ztot2, out);
}